// Round 1
// baseline (980.595 us; speedup 1.0000x reference)
//
#include <hip/hip_runtime.h>

#define NROWS 2097152
#define DDIM  64

// 16 lanes per row, each lane owns one float4 (4 columns).
// A wave (64 lanes) covers 4 consecutive rows -> each global_load_dwordx4
// issued by the wave touches 1 KiB contiguous memory: perfect coalescing.
__global__ __launch_bounds__(256) void hyper_dist_kernel(
        const float* __restrict__ B,
        const float* __restrict__ T,
        const float* __restrict__ M,
        float* __restrict__ ws_sum) {
    const int tid    = threadIdx.x;
    const int lane16 = tid & 15;              // column-group within the row

    // metric slice for this lane's 4 columns (M[0] = -1, rest = +1)
    const float4 m = reinterpret_cast<const float4*>(M)[lane16];

    const int  groupsPerBlock = blockDim.x >> 4;   // 16 row-groups per 256-thread block
    const int  groupInBlock   = tid >> 4;
    long long  row    = (long long)blockIdx.x * groupsPerBlock + groupInBlock;
    const long long rowStride = (long long)gridDim.x * groupsPerBlock;

    float acc = 0.0f;
    for (; row < NROWS; row += rowStride) {
        const float4 b = reinterpret_cast<const float4*>(B)[row * (DDIM / 4) + lane16];
        const float4 t = reinterpret_cast<const float4*>(T)[row * (DDIM / 4) + lane16];
        float p = m.x * b.x * t.x + m.y * b.y * t.y
                + m.z * b.z * t.z + m.w * b.w * t.w;
        // reduce the metric-weighted inner product across the 16-lane group
        p += __shfl_xor(p, 1);
        p += __shfl_xor(p, 2);
        p += __shfl_xor(p, 4);
        p += __shfl_xor(p, 8);
        if (lane16 == 0) {
            float x = fmaxf(-p, 1.0f);
            acc += acoshf(x);
        }
    }

    // full-wave butterfly (non-leader lanes hold 0.0f, harmless)
    acc += __shfl_xor(acc, 1);
    acc += __shfl_xor(acc, 2);
    acc += __shfl_xor(acc, 4);
    acc += __shfl_xor(acc, 8);
    acc += __shfl_xor(acc, 16);
    acc += __shfl_xor(acc, 32);

    // block reduce across the 4 waves via LDS
    __shared__ float wave_sums[4];
    const int waveId = tid >> 6;
    if ((tid & 63) == 0) wave_sums[waveId] = acc;
    __syncthreads();
    if (tid == 0) {
        float s = wave_sums[0] + wave_sums[1] + wave_sums[2] + wave_sums[3];
        atomicAdd(ws_sum, s);   // device-scope by default on CDNA
    }
}

__global__ void hyper_dist_finalize(const float* __restrict__ ws_sum,
                                    float* __restrict__ out) {
    out[0] = ws_sum[0] * (1.0f / (float)NROWS);
}

extern "C" void kernel_launch(void* const* d_in, const int* in_sizes, int n_in,
                              void* d_out, int out_size, void* d_ws, size_t ws_size,
                              hipStream_t stream) {
    const float* B = (const float*)d_in[0];   // batch_features  [N, 64] f32
    const float* T = (const float*)d_in[1];   // target_features [N, 64] f32
    const float* M = (const float*)d_in[2];   // metric          [64]    f32
    float* out = (float*)d_out;
    float* ws  = (float*)d_ws;

    // d_ws is re-poisoned to 0xAA before every timed launch -> must zero it.
    hipMemsetAsync(ws, 0, sizeof(float), stream);

    // 8192 blocks x 256 threads = 32768 waves; each block handles 16 rows
    // per grid-stride iteration -> 16 iterations over N.
    hyper_dist_kernel<<<8192, 256, 0, stream>>>(B, T, M, ws);
    hyper_dist_finalize<<<1, 1, 0, stream>>>(ws, out);
}